// Round 2
// baseline (281.610 us; speedup 1.0000x reference)
//
#include <hip/hip_runtime.h>
#include <stdint.h>

// CapsuleLayer dynamic routing, MI355X. fp32 in/out (per reference dtypes).
// B=256, N=10, I=1152, D=16, K(Din)=8, ROUTINGS=3.
// K1: u_hat = W x  (b/i-tiled for W reuse), stored bf16 in ws (94.4 MB).
// K2: block-per-b; 3 fused routing sweeps streaming u_hat; blog in LDS.

#define BN 256
#define NN 10
#define II 1152
#define DD 16
#define KK 8

typedef unsigned short ushort_t;
typedef unsigned int uint_t;

__device__ __forceinline__ float bflo(uint_t u) {
    union { uint_t i; float f; } v; v.i = u << 16; return v.f;
}
__device__ __forceinline__ float bfhi(uint_t u) {
    union { uint_t i; float f; } v; v.i = u & 0xffff0000u; return v.f;
}
__device__ __forceinline__ uint_t f2bf(float f) {  // RTNE bf16 (finite values)
    union { float f; uint_t i; } v; v.f = f;
    uint_t x = v.i;
    return (x + 0x7fffu + ((x >> 16) & 1u)) >> 16;
}

// ---------------- K1: u_hat[b][n][i][d] = sum_k W[n][i][d][k] * x[b][i][k] ---
// grid (16 i-tiles, C/16 b-tiles), 256 threads. Each block: 16 b x 72 i x all n,d.
// u_hat stored as bf16 in ws, layout [b_local][n][i][d].
__global__ __launch_bounds__(256) void caps_uhat(const float* __restrict__ xg,
                                                 const float* __restrict__ wg,
                                                 ushort_t* __restrict__ u, int b0)
{
    __shared__ float xs[16 * 648];  // [b_l][i_l*9 + k], pad 9 breaks bank conflicts
    const int tid = threadIdx.x;
    const int i0 = blockIdx.x * 72;
    const int bbase = b0 + blockIdx.y * 16;

    for (int e = tid; e < 16 * 576; e += 256) {
        int bl = e / 576, r = e - bl * 576;
        int il = r >> 3, k = r & 7;
        xs[bl * 648 + il * 9 + k] =
            xg[(size_t)(bbase + bl) * (II * KK) + (size_t)i0 * KK + r];
    }
    __syncthreads();

    for (int t = 0; t < 45; ++t) {
        int idx = t * 256 + tid;           // i_l innermost -> coalesced stores
        int il = idx % 72;
        int q = idx / 72;
        int bl = q & 15;                   // b next -> W row reuse stays in L1/L2
        int n = q >> 4;
        int i = i0 + il;

        const float4* wp = (const float4*)(wg + (size_t)(n * II + i) * (DD * KK));
        float xv[8];
#pragma unroll
        for (int k = 0; k < 8; ++k) xv[k] = xs[bl * 648 + il * 9 + k];

        float acc[16];
#pragma unroll
        for (int d = 0; d < 16; ++d) {
            float4 wa = wp[2 * d], wb = wp[2 * d + 1];
            float s;
            s  = wa.x * xv[0] + wa.y * xv[1] + wa.z * xv[2] + wa.w * xv[3];
            s += wb.x * xv[4] + wb.y * xv[5] + wb.z * xv[6] + wb.w * xv[7];
            acc[d] = s;
        }
        uint_t p[8];
#pragma unroll
        for (int j = 0; j < 8; ++j)
            p[j] = f2bf(acc[2 * j]) | (f2bf(acc[2 * j + 1]) << 16);

        int blocal = blockIdx.y * 16 + bl;  // chunk-local b index into ws
        uint4* dst = (uint4*)(u + ((size_t)(blocal * NN + n) * II + i) * DD);
        dst[0] = make_uint4(p[0], p[1], p[2], p[3]);
        dst[1] = make_uint4(p[4], p[5], p[6], p[7]);
    }
}

// ---------------- K2: routing sweeps ----------------------------------------
// block per b, 512 threads. 4-lane groups own d-slices of 4; 128 groups x 9 i-steps.
__device__ __forceinline__ void reduce_squash(float sp[NN][4], int tid,
                                              float* red, float* s_s,
                                              float* o_s, float* scale_s,
                                              float* outp)
{
#pragma unroll
    for (int m = 4; m <= 32; m <<= 1)
#pragma unroll
        for (int n = 0; n < NN; ++n)
#pragma unroll
            for (int j = 0; j < 4; ++j)
                sp[n][j] += __shfl_xor(sp[n][j], m, 64);

    const int lane = tid & 63, wv = tid >> 6, ld = tid & 3;
    if (lane < 4) {
#pragma unroll
        for (int n = 0; n < NN; ++n)
#pragma unroll
            for (int j = 0; j < 4; ++j)
                red[(wv * NN + n) * 16 + ld * 4 + j] = sp[n][j];
    }
    __syncthreads();
    if (tid < 160) {
        float v = 0.f;
#pragma unroll
        for (int w = 0; w < 8; ++w) v += red[(w * NN + (tid >> 4)) * 16 + (tid & 15)];
        s_s[tid] = v;
    }
    __syncthreads();
    if (tid < NN) {
        float ns = 0.f;
#pragma unroll
        for (int d = 0; d < 16; ++d) { float x = s_s[tid * 16 + d]; ns += x * x; }
        scale_s[tid] = sqrtf(ns) / (1.0f + ns);  // v*scale == v/|v| * ns/(1+ns)
    }
    __syncthreads();
    if (tid < 160) {
        float val = s_s[tid] * scale_s[tid >> 4];
        if (outp) outp[tid] = val;
        else      o_s[tid] = val;
    }
    __syncthreads();
}

__global__ __launch_bounds__(512) void caps_route(const ushort_t* __restrict__ u,
                                                  float* __restrict__ out, int b0)
{
    __shared__ float blog[NN * II];     // 45 KB: b-logits persist across sweeps
    __shared__ float red[8 * 160];
    __shared__ float s_s[160];
    __shared__ float o_s[160];
    __shared__ float scale_s[NN];

    const int tid = threadIdx.x;
    const int g = tid >> 2, ld = tid & 3;
    const ushort_t* ub = u + (size_t)blockIdx.x * (NN * II * DD);

    float sp[NN][4];

    // ---- sweep 0: c uniform = 1/N ----
#pragma unroll
    for (int n = 0; n < NN; ++n)
#pragma unroll
        for (int j = 0; j < 4; ++j) sp[n][j] = 0.f;

    for (int ii = 0; ii < 9; ++ii) {
        int i = g + ii * 128;
#pragma unroll
        for (int n = 0; n < NN; ++n) {
            uint2 r = *(const uint2*)(ub + (n * II + i) * DD + ld * 4);
            sp[n][0] += bflo(r.x); sp[n][1] += bfhi(r.x);
            sp[n][2] += bflo(r.y); sp[n][3] += bfhi(r.y);
        }
    }
#pragma unroll
    for (int n = 0; n < NN; ++n)
#pragma unroll
        for (int j = 0; j < 4; ++j) sp[n][j] *= 0.1f;
    reduce_squash(sp, tid, red, s_s, o_s, scale_s, nullptr);

    float oreg[NN][4];
#pragma unroll
    for (int n = 0; n < NN; ++n)
#pragma unroll
        for (int j = 0; j < 4; ++j) oreg[n][j] = o_s[(n << 4) + (ld << 2) + j];

    // ---- sweep 1: a0 = <o0,u>; blog = a0; c = softmax(a0); s += c*u ----
#pragma unroll
    for (int n = 0; n < NN; ++n)
#pragma unroll
        for (int j = 0; j < 4; ++j) sp[n][j] = 0.f;

    for (int ii = 0; ii < 9; ++ii) {
        int i = g + ii * 128;
        float uu[NN][4], p[NN];
#pragma unroll
        for (int n = 0; n < NN; ++n) {
            uint2 r = *(const uint2*)(ub + (n * II + i) * DD + ld * 4);
            uu[n][0] = bflo(r.x); uu[n][1] = bfhi(r.x);
            uu[n][2] = bflo(r.y); uu[n][3] = bfhi(r.y);
            p[n] = uu[n][0] * oreg[n][0] + uu[n][1] * oreg[n][1]
                 + uu[n][2] * oreg[n][2] + uu[n][3] * oreg[n][3];
        }
        float a[NN];
#pragma unroll
        for (int n = 0; n < NN; ++n) {
            float t = p[n] + __shfl_xor(p[n], 1, 64);
            a[n] = t + __shfl_xor(t, 2, 64);
        }
        if (ld == 0) {
#pragma unroll
            for (int n = 0; n < NN; ++n) blog[n * II + i] = a[n];
        }
        float m = a[0];
#pragma unroll
        for (int n = 1; n < NN; ++n) m = fmaxf(m, a[n]);
        float c[NN], ssum = 0.f;
#pragma unroll
        for (int n = 0; n < NN; ++n) { c[n] = __expf(a[n] - m); ssum += c[n]; }
        float inv = 1.0f / ssum;
#pragma unroll
        for (int n = 0; n < NN; ++n)
#pragma unroll
            for (int j = 0; j < 4; ++j) sp[n][j] += (c[n] * inv) * uu[n][j];
    }
    reduce_squash(sp, tid, red, s_s, o_s, scale_s, nullptr);
#pragma unroll
    for (int n = 0; n < NN; ++n)
#pragma unroll
        for (int j = 0; j < 4; ++j) oreg[n][j] = o_s[(n << 4) + (ld << 2) + j];

    // ---- sweep 2: b2 = blog + <o1,u>; c = softmax(b2); s += c*u; out ----
#pragma unroll
    for (int n = 0; n < NN; ++n)
#pragma unroll
        for (int j = 0; j < 4; ++j) sp[n][j] = 0.f;

    for (int ii = 0; ii < 9; ++ii) {
        int i = g + ii * 128;
        float uu[NN][4], p[NN];
#pragma unroll
        for (int n = 0; n < NN; ++n) {
            uint2 r = *(const uint2*)(ub + (n * II + i) * DD + ld * 4);
            uu[n][0] = bflo(r.x); uu[n][1] = bfhi(r.x);
            uu[n][2] = bflo(r.y); uu[n][3] = bfhi(r.y);
            p[n] = uu[n][0] * oreg[n][0] + uu[n][1] * oreg[n][1]
                 + uu[n][2] * oreg[n][2] + uu[n][3] * oreg[n][3];
        }
        float a[NN];
#pragma unroll
        for (int n = 0; n < NN; ++n) {
            float t = p[n] + __shfl_xor(p[n], 1, 64);
            a[n] = t + __shfl_xor(t, 2, 64) + blog[n * II + i];
        }
        float m = a[0];
#pragma unroll
        for (int n = 1; n < NN; ++n) m = fmaxf(m, a[n]);
        float c[NN], ssum = 0.f;
#pragma unroll
        for (int n = 0; n < NN; ++n) { c[n] = __expf(a[n] - m); ssum += c[n]; }
        float inv = 1.0f / ssum;
#pragma unroll
        for (int n = 0; n < NN; ++n)
#pragma unroll
            for (int j = 0; j < 4; ++j) sp[n][j] += (c[n] * inv) * uu[n][j];
    }
    reduce_squash(sp, tid, red, s_s, o_s, scale_s,
                  out + (size_t)(b0 + blockIdx.x) * (NN * DD));
}

extern "C" void kernel_launch(void* const* d_in, const int* in_sizes, int n_in,
                              void* d_out, int out_size, void* d_ws, size_t ws_size,
                              hipStream_t stream)
{
    const float* xg = (const float*)d_in[0];  // inputs [B,I,K] = 2,359,296 elems
    const float* wg = (const float*)d_in[1];  // W [N,I,D,K]   = 1,474,560 elems
    if (n_in >= 2 && in_sizes[0] == NN * II * DD * KK) {  // defensive: order swapped
        const float* t = xg; xg = wg; wg = t;
    }
    float* outp = (float*)d_out;
    ushort_t* uws = (ushort_t*)d_ws;

    const size_t perB = (size_t)NN * II * DD * 2;  // 368,640 B per batch elem (bf16)
    int C = 256;
    if (ws_size < (size_t)256 * perB) {
        C = (int)(ws_size / perB);
        C &= ~15;
        if (C < 16) C = 16;
    }
    for (int b0 = 0; b0 < BN; b0 += C) {
        int c = (BN - b0 < C) ? (BN - b0) : C;
        dim3 g1(16, c / 16);
        caps_uhat<<<g1, 256, 0, stream>>>(xg, wg, uws, b0);
        caps_route<<<c, 512, 0, stream>>>(uws, outp, b0);
    }
}

// Round 3
// 213.514 us; speedup vs baseline: 1.3189x; 1.3189x over previous
//
#include <hip/hip_runtime.h>
#include <stdint.h>

// CapsuleLayer dynamic routing, MI355X. fp32 in/out.
// B=256, N=10, I=1152, D=16, K(Din)=8, ROUTINGS=3.
// R3: occupancy fix. K1 thread-per-(n,i,4b). Routing = 3 streaming sweep
// kernels (grid B*9) + tiny finalize; blog eliminated via osum = o0+o1
// (exact: b starts at 0 so logits are <sum of prior outputs, u>).

#define BN 256
#define NN 10
#define II 1152
#define DD 16
#define KK 8
#define CHI 128        // i per sweep block
#define NCH (II / CHI) // 9

typedef unsigned short ushort_t;
typedef unsigned int uint_t;

__device__ __forceinline__ float bflo(uint_t u) {
    union { uint_t i; float f; } v; v.i = u << 16; return v.f;
}
__device__ __forceinline__ float bfhi(uint_t u) {
    union { uint_t i; float f; } v; v.i = u & 0xffff0000u; return v.f;
}
__device__ __forceinline__ uint_t f2bf(float f) {  // RTNE bf16
    union { float f; uint_t i; } v; v.f = f;
    uint_t x = v.i;
    return (x + 0x7fffu + ((x >> 16) & 1u)) >> 16;
}

// ---------------- K1: u_hat[b][n][i][d] = sum_k W[n][i][d][k] * x[b][i][k] ---
// thread t -> (bq, n, i), i innermost; handles b = 4*bq .. 4*bq+3.
// grid = c*45/4 blocks of 256 (c multiple of 16). u stored bf16 [b_loc][n][i][d].
__global__ __launch_bounds__(256) void caps_uhat(const float* __restrict__ xg,
                                                 const float* __restrict__ wg,
                                                 ushort_t* __restrict__ u, int b0)
{
    int t = blockIdx.x * 256 + threadIdx.x;
    int i = t % II;
    int r = t / II;
    int n = r % NN;
    int bl = (r / NN) * 4;   // chunk-local base b

    const float4* xp = (const float4*)(xg + ((size_t)(b0 + bl) * II + i) * KK);
    float xv[4][8];
#pragma unroll
    for (int j = 0; j < 4; ++j) {
        float4 a = xp[j * 2304];        // II*KK/4 = 2304 float4 per b
        float4 b = xp[j * 2304 + 1];
        xv[j][0] = a.x; xv[j][1] = a.y; xv[j][2] = a.z; xv[j][3] = a.w;
        xv[j][4] = b.x; xv[j][5] = b.y; xv[j][6] = b.z; xv[j][7] = b.w;
    }
    const float4* wp = (const float4*)(wg + (size_t)(n * II + i) * (DD * KK));
    uint_t p[4][8];
#pragma unroll
    for (int d = 0; d < DD; ++d) {
        float4 wa = wp[2 * d], wb = wp[2 * d + 1];
#pragma unroll
        for (int j = 0; j < 4; ++j) {
            float s = wa.x * xv[j][0] + wa.y * xv[j][1]
                    + wa.z * xv[j][2] + wa.w * xv[j][3]
                    + wb.x * xv[j][4] + wb.y * xv[j][5]
                    + wb.z * xv[j][6] + wb.w * xv[j][7];
            uint_t h = f2bf(s);
            if (d & 1) p[j][d >> 1] |= h << 16;
            else       p[j][d >> 1]  = h;
        }
    }
#pragma unroll
    for (int j = 0; j < 4; ++j) {
        uint4* dst = (uint4*)(u + (((size_t)(bl + j) * NN + n) * II + i) * DD);
        dst[0] = make_uint4(p[j][0], p[j][1], p[j][2], p[j][3]);
        dst[1] = make_uint4(p[j][4], p[j][5], p[j][6], p[j][7]);
    }
}

// ---- block reduction of sp[NN][4] over 64 groups -> 160 floats to part -----
__device__ __forceinline__ void block_reduce_part(float sp[NN][4], int tid,
                                                  float* red,
                                                  float* __restrict__ partp)
{
#pragma unroll
    for (int m = 4; m <= 32; m <<= 1)
#pragma unroll
        for (int n = 0; n < NN; ++n)
#pragma unroll
            for (int j = 0; j < 4; ++j)
                sp[n][j] += __shfl_xor(sp[n][j], m, 64);

    const int lane = tid & 63, wv = tid >> 6, ld = tid & 3;
    if (lane < 4) {
#pragma unroll
        for (int n = 0; n < NN; ++n)
#pragma unroll
            for (int j = 0; j < 4; ++j)
                red[(wv * NN + n) * 16 + ld * 4 + j] = sp[n][j];
    }
    __syncthreads();
    if (tid < 160) {
        int n = tid >> 4, dd = tid & 15;
        float v = 0.f;
#pragma unroll
        for (int w = 0; w < 4; ++w) v += red[(w * NN + n) * 16 + dd];
        partp[tid] = v;
    }
}

// ---------------- sweep 0: s-partial = 0.1 * sum_i u ------------------------
__global__ __launch_bounds__(256) void caps_sweep0(const ushort_t* __restrict__ u,
                                                   float* __restrict__ part, int b0)
{
    __shared__ float red[4 * 160];
    const int tid = threadIdx.x, g = tid >> 2, ld = tid & 3;
    const int cb = blockIdx.x / NCH, ch = blockIdx.x % NCH;
    const ushort_t* ub = u + (size_t)cb * (NN * II * DD);

    float sp[NN][4];
#pragma unroll
    for (int n = 0; n < NN; ++n)
#pragma unroll
        for (int j = 0; j < 4; ++j) sp[n][j] = 0.f;

#pragma unroll
    for (int step = 0; step < 2; ++step) {
        int i = ch * CHI + step * 64 + g;
#pragma unroll
        for (int n = 0; n < NN; ++n) {
            uint2 r = *(const uint2*)(ub + ((size_t)(n * II + i)) * DD + ld * 4);
            sp[n][0] += bflo(r.x); sp[n][1] += bfhi(r.x);
            sp[n][2] += bflo(r.y); sp[n][3] += bfhi(r.y);
        }
    }
#pragma unroll
    for (int n = 0; n < NN; ++n)
#pragma unroll
        for (int j = 0; j < 4; ++j) sp[n][j] *= 0.1f;

    block_reduce_part(sp, tid, red,
                      part + ((size_t)(b0 + cb) * NCH + ch) * 160);
}

// ---------------- sweep 1/2: c = softmax_n(<osum,u>), s-partial = sum c*u ----
__global__ __launch_bounds__(256) void caps_sweep(const ushort_t* __restrict__ u,
                                                  const float* __restrict__ osum,
                                                  float* __restrict__ part, int b0)
{
    __shared__ float red[4 * 160];
    const int tid = threadIdx.x, g = tid >> 2, ld = tid & 3;
    const int cb = blockIdx.x / NCH, ch = blockIdx.x % NCH;
    const int b = b0 + cb;
    const ushort_t* ub = u + (size_t)cb * (NN * II * DD);

    float oreg[NN][4];
    const float4* op = (const float4*)(osum + (size_t)b * 160);
#pragma unroll
    for (int n = 0; n < NN; ++n) {
        float4 o4 = op[n * 4 + ld];
        oreg[n][0] = o4.x; oreg[n][1] = o4.y; oreg[n][2] = o4.z; oreg[n][3] = o4.w;
    }

    float sp[NN][4];
#pragma unroll
    for (int n = 0; n < NN; ++n)
#pragma unroll
        for (int j = 0; j < 4; ++j) sp[n][j] = 0.f;

#pragma unroll
    for (int step = 0; step < 2; ++step) {
        int i = ch * CHI + step * 64 + g;
        float uu[NN][4], p[NN];
#pragma unroll
        for (int n = 0; n < NN; ++n) {
            uint2 r = *(const uint2*)(ub + ((size_t)(n * II + i)) * DD + ld * 4);
            uu[n][0] = bflo(r.x); uu[n][1] = bfhi(r.x);
            uu[n][2] = bflo(r.y); uu[n][3] = bfhi(r.y);
            p[n] = uu[n][0] * oreg[n][0] + uu[n][1] * oreg[n][1]
                 + uu[n][2] * oreg[n][2] + uu[n][3] * oreg[n][3];
        }
        float a[NN];
#pragma unroll
        for (int n = 0; n < NN; ++n) {
            float t2 = p[n] + __shfl_xor(p[n], 1, 64);
            a[n] = t2 + __shfl_xor(t2, 2, 64);
        }
        float m = a[0];
#pragma unroll
        for (int n = 1; n < NN; ++n) m = fmaxf(m, a[n]);
        float c[NN], ssum = 0.f;
#pragma unroll
        for (int n = 0; n < NN; ++n) { c[n] = __expf(a[n] - m); ssum += c[n]; }
        float inv = 1.0f / ssum;
#pragma unroll
        for (int n = 0; n < NN; ++n) {
            float w = c[n] * inv;
#pragma unroll
            for (int j = 0; j < 4; ++j) sp[n][j] += w * uu[n][j];
        }
    }
    block_reduce_part(sp, tid, red,
                      part + ((size_t)b * NCH + ch) * 160);
}

// ---------------- finalize: reduce 9 partials, squash, update osum/out -------
// grid c blocks of 192 (160 active). mode 0: osum=o ; 1: osum+=o ; 2: out=o.
__global__ __launch_bounds__(192) void caps_fin(const float* __restrict__ part,
                                                float* __restrict__ osum,
                                                float* __restrict__ out,
                                                int b0, int mode)
{
    const int b = b0 + blockIdx.x;
    const int t = threadIdx.x;
    if (t < 160) {
        float v = 0.f;
#pragma unroll
        for (int ch = 0; ch < NCH; ++ch)
            v += part[((size_t)b * NCH + ch) * 160 + t];
        float sq = v * v;
#pragma unroll
        for (int m = 1; m <= 8; m <<= 1) sq += __shfl_xor(sq, m, 64);
        float scale = sqrtf(sq) / (1.0f + sq);   // squash: v*|v|/(1+|v|^2)
        float o = v * scale;
        if (mode == 0)      osum[(size_t)b * 160 + t]  = o;
        else if (mode == 1) osum[(size_t)b * 160 + t] += o;
        else                out[(size_t)b * 160 + t]   = o;
    }
}

extern "C" void kernel_launch(void* const* d_in, const int* in_sizes, int n_in,
                              void* d_out, int out_size, void* d_ws, size_t ws_size,
                              hipStream_t stream)
{
    const float* xg = (const float*)d_in[0];  // [B,I,K]
    const float* wg = (const float*)d_in[1];  // [N,I,D,K]
    if (n_in >= 2 && in_sizes[0] == NN * II * DD * KK) {
        const float* t = xg; xg = wg; wg = t;
    }
    float* outp = (float*)d_out;

    const size_t perB   = (size_t)NN * II * DD * 2;        // 368,640 B bf16 u per b
    const size_t partB  = (size_t)BN * NCH * 160 * 4;      // 1,474,560 B
    const size_t osumB  = (size_t)BN * 160 * 4;            // 163,840 B
    size_t avail = (ws_size > partB + osumB) ? ws_size - partB - osumB : 0;
    int C = 256;
    if (avail < (size_t)256 * perB) {
        C = (int)(avail / perB);
        C &= ~15;
        if (C < 16) C = 16;
    }
    ushort_t* uws = (ushort_t*)d_ws;
    float* part = (float*)((char*)d_ws + (size_t)C * perB);
    float* osum = part + (size_t)BN * NCH * 160;

    for (int b0 = 0; b0 < BN; b0 += C) {
        int c = (BN - b0 < C) ? (BN - b0) : C;
        caps_uhat <<<c * 45 / 4, 256, 0, stream>>>(xg, wg, uws, b0);
        caps_sweep0<<<c * NCH,   256, 0, stream>>>(uws, part, b0);
        caps_fin  <<<c,          192, 0, stream>>>(part, osum, outp, b0, 0);
        caps_sweep <<<c * NCH,   256, 0, stream>>>(uws, osum, part, b0);
        caps_fin  <<<c,          192, 0, stream>>>(part, osum, outp, b0, 1);
        caps_sweep <<<c * NCH,   256, 0, stream>>>(uws, osum, part, b0);
        caps_fin  <<<c,          192, 0, stream>>>(part, osum, outp, b0, 2);
    }
}

// Round 4
// 210.544 us; speedup vs baseline: 1.3375x; 1.0141x over previous
//
#include <hip/hip_runtime.h>
#include <stdint.h>

// CapsuleLayer dynamic routing, MI355X. fp32 in/out.
// B=256, N=10, I=1152, D=16, K(Din)=8, ROUTINGS=3.
// R4: K1 fuses sweep0 (uniform softmax) + coalesced W geometry (d-quad lanes);
// sweeps inline the squash-finalize; 4 launches total.

#define BN 256
#define NN 10
#define II 1152
#define DD 16
#define KK 8
#define NCH 9          // sweep chunks of 128 i

typedef unsigned short ushort_t;
typedef unsigned int uint_t;

__device__ __forceinline__ float bflo(uint_t u) {
    union { uint_t i; float f; } v; v.i = u << 16; return v.f;
}
__device__ __forceinline__ float bfhi(uint_t u) {
    union { uint_t i; float f; } v; v.i = u & 0xffff0000u; return v.f;
}
__device__ __forceinline__ uint_t f2bf(float f) {  // RTNE bf16
    union { float f; uint_t i; } v; v.f = f;
    uint_t x = v.i;
    return (x + 0x7fffu + ((x >> 16) & 1u)) >> 16;
}

// ---------------- K1 + sweep0 -----------------------------------------------
// block = (n, b-pair), n-major (consecutive blocks same n -> XCD-spread).
// 256 thr: g=tid>>2 (i-group), ld=tid&3 (d-quad). 18 chunks of 64 i.
// Writes u bf16 [b_loc][n][i][d] and part0[b][n*16+d] = 0.1*sum_i u (fp32).
__global__ __launch_bounds__(256) void caps_uhat_s0(const float* __restrict__ xg,
                                                    const float* __restrict__ wg,
                                                    ushort_t* __restrict__ u,
                                                    float* __restrict__ part0,
                                                    int b0, int c2)
{
    __shared__ float red[128];
    const int tid = threadIdx.x;
    const int g = tid >> 2, ld = tid & 3;
    const int n = blockIdx.x / c2;
    const int bl = (blockIdx.x % c2) * 2;   // chunk-local b base (2 b's)

    float p0[2][4];
#pragma unroll
    for (int bb = 0; bb < 2; ++bb)
#pragma unroll
        for (int dj = 0; dj < 4; ++dj) p0[bb][dj] = 0.f;

    for (int ch = 0; ch < 18; ++ch) {
        int i = ch * 64 + g;
        // x: 4 lanes of a group read the same 32 B -> coalescer merges.
        float4 xa[2], xb[2];
#pragma unroll
        for (int bb = 0; bb < 2; ++bb) {
            const float4* xp = (const float4*)(xg + ((size_t)(b0 + bl + bb) * II + i) * KK);
            xa[bb] = xp[0]; xb[bb] = xp[1];
        }
        // W row (n,i): 512 B; lane ld takes bytes [ld*128, ld*128+128) -> wave
        // covers 16 consecutive rows contiguously.
        const float4* wp = (const float4*)(wg + (size_t)(n * II + i) * (DD * KK));
        uint_t q[2][2];
#pragma unroll
        for (int dj = 0; dj < 4; ++dj) {
            int d = ld * 4 + dj;
            float4 wa = wp[2 * d], wb = wp[2 * d + 1];
#pragma unroll
            for (int bb = 0; bb < 2; ++bb) {
                float s = wa.x * xa[bb].x + wa.y * xa[bb].y
                        + wa.z * xa[bb].z + wa.w * xa[bb].w
                        + wb.x * xb[bb].x + wb.y * xb[bb].y
                        + wb.z * xb[bb].z + wb.w * xb[bb].w;
                p0[bb][dj] += s;
                uint_t h = f2bf(s);
                if (dj & 1) q[bb][dj >> 1] |= h << 16;
                else        q[bb][dj >> 1]  = h;
            }
        }
#pragma unroll
        for (int bb = 0; bb < 2; ++bb) {
            uint2* dst = (uint2*)(u + (((size_t)(bl + bb) * NN + n) * II + i) * DD + ld * 4);
            *dst = make_uint2(q[bb][0], q[bb][1]);
        }
    }

    // reduce p0 over i-groups: within wave (masks 4..32), then across 4 waves.
#pragma unroll
    for (int m = 4; m <= 32; m <<= 1)
#pragma unroll
        for (int bb = 0; bb < 2; ++bb)
#pragma unroll
            for (int dj = 0; dj < 4; ++dj)
                p0[bb][dj] += __shfl_xor(p0[bb][dj], m, 64);

    const int lane = tid & 63, wv = tid >> 6;
    if (lane < 4) {
#pragma unroll
        for (int bb = 0; bb < 2; ++bb)
#pragma unroll
            for (int dj = 0; dj < 4; ++dj)
                red[wv * 32 + ld * 8 + bb * 4 + dj] = p0[bb][dj];
    }
    __syncthreads();
    if (tid < 32) {
        int bb = tid >> 4, d = tid & 15;
        float v = 0.f;
#pragma unroll
        for (int w = 0; w < 4; ++w)
            v += red[w * 32 + (d >> 2) * 8 + bb * 4 + (d & 3)];
        part0[(size_t)(b0 + bl + bb) * 160 + n * 16 + d] = 0.1f * v;
    }
}

// ---- block reduction of sp[NN][4] over 64 groups -> 160 floats -------------
__device__ __forceinline__ void block_reduce_part(float sp[NN][4], int tid,
                                                  float* red,
                                                  float* __restrict__ partp)
{
#pragma unroll
    for (int m = 4; m <= 32; m <<= 1)
#pragma unroll
        for (int n = 0; n < NN; ++n)
#pragma unroll
            for (int j = 0; j < 4; ++j)
                sp[n][j] += __shfl_xor(sp[n][j], m, 64);

    const int lane = tid & 63, wv = tid >> 6, ld = tid & 3;
    if (lane < 4) {
#pragma unroll
        for (int n = 0; n < NN; ++n)
#pragma unroll
            for (int j = 0; j < 4; ++j)
                red[(wv * NN + n) * 16 + ld * 4 + j] = sp[n][j];
    }
    __syncthreads();
    if (tid < 160) {
        int n = tid >> 4, dd = tid & 15;
        float v = 0.f;
#pragma unroll
        for (int w = 0; w < 4; ++w) v += red[(w * NN + n) * 16 + dd];
        partp[tid] = v;
    }
}

// ---------------- sweep r=1,2: inline squash of prior partials --------------
// o = squash(part0[b]); if p1: o += squash(sum_ch p1[b][ch]).
// Then c = softmax_n(<o,u>), partial s = sum c*u over this i-chunk.
__global__ __launch_bounds__(256) void caps_sweep(const ushort_t* __restrict__ u,
                                                  const float* __restrict__ p0,
                                                  const float* __restrict__ p1,
                                                  float* __restrict__ pout, int b0)
{
    __shared__ float red[4 * 160];
    __shared__ float o_s[160];
    const int tid = threadIdx.x, g = tid >> 2, ld = tid & 3;
    const int cb = blockIdx.x / NCH, ch = blockIdx.x % NCH;
    const int b = b0 + cb;
    const ushort_t* ub = u + (size_t)cb * (NN * II * DD);

    if (tid < 160) {
        float v = p0[(size_t)b * 160 + tid];
        float sq = v * v;
#pragma unroll
        for (int m = 1; m <= 8; m <<= 1) sq += __shfl_xor(sq, m, 64);
        float o = v * (sqrtf(sq) / (1.0f + sq));
        if (p1) {
            float v1 = 0.f;
#pragma unroll
            for (int c2 = 0; c2 < NCH; ++c2)
                v1 += p1[((size_t)b * NCH + c2) * 160 + tid];
            float sq1 = v1 * v1;
#pragma unroll
            for (int m = 1; m <= 8; m <<= 1) sq1 += __shfl_xor(sq1, m, 64);
            o += v1 * (sqrtf(sq1) / (1.0f + sq1));
        }
        o_s[tid] = o;
    }
    __syncthreads();

    float oreg[NN][4];
#pragma unroll
    for (int n = 0; n < NN; ++n)
#pragma unroll
        for (int j = 0; j < 4; ++j) oreg[n][j] = o_s[(n << 4) + (ld << 2) + j];

    // preload both i-steps' u (hide latency)
    uint2 r0[NN], r1[NN];
    {
        int i0 = ch * 128 + g;
#pragma unroll
        for (int n = 0; n < NN; ++n) {
            r0[n] = *(const uint2*)(ub + ((size_t)(n * II + i0)) * DD + ld * 4);
            r1[n] = *(const uint2*)(ub + ((size_t)(n * II + i0 + 64)) * DD + ld * 4);
        }
    }

    float sp[NN][4];
#pragma unroll
    for (int n = 0; n < NN; ++n)
#pragma unroll
        for (int j = 0; j < 4; ++j) sp[n][j] = 0.f;

#pragma unroll
    for (int step = 0; step < 2; ++step) {
        float uu[NN][4], p[NN];
#pragma unroll
        for (int n = 0; n < NN; ++n) {
            uint2 r = step ? r1[n] : r0[n];
            uu[n][0] = bflo(r.x); uu[n][1] = bfhi(r.x);
            uu[n][2] = bflo(r.y); uu[n][3] = bfhi(r.y);
            p[n] = uu[n][0] * oreg[n][0] + uu[n][1] * oreg[n][1]
                 + uu[n][2] * oreg[n][2] + uu[n][3] * oreg[n][3];
        }
        float a[NN];
#pragma unroll
        for (int n = 0; n < NN; ++n) {
            float t2 = p[n] + __shfl_xor(p[n], 1, 64);
            a[n] = t2 + __shfl_xor(t2, 2, 64);
        }
        float m = a[0];
#pragma unroll
        for (int n = 1; n < NN; ++n) m = fmaxf(m, a[n]);
        float c[NN], ssum = 0.f;
#pragma unroll
        for (int n = 0; n < NN; ++n) { c[n] = __expf(a[n] - m); ssum += c[n]; }
        float inv = 1.0f / ssum;
#pragma unroll
        for (int n = 0; n < NN; ++n) {
            float w = c[n] * inv;
#pragma unroll
            for (int j = 0; j < 4; ++j) sp[n][j] += w * uu[n][j];
        }
    }
    block_reduce_part(sp, tid, red, pout + ((size_t)b * NCH + ch) * 160);
}

// ---------------- output: squash(sum_ch part2) ------------------------------
__global__ __launch_bounds__(192) void caps_out(const float* __restrict__ p2,
                                                float* __restrict__ out, int b0)
{
    const int b = b0 + blockIdx.x;
    const int t = threadIdx.x;
    if (t < 160) {
        float v = 0.f;
#pragma unroll
        for (int ch = 0; ch < NCH; ++ch)
            v += p2[((size_t)b * NCH + ch) * 160 + t];
        float sq = v * v;
#pragma unroll
        for (int m = 1; m <= 8; m <<= 1) sq += __shfl_xor(sq, m, 64);
        out[(size_t)b * 160 + t] = v * (sqrtf(sq) / (1.0f + sq));
    }
}

extern "C" void kernel_launch(void* const* d_in, const int* in_sizes, int n_in,
                              void* d_out, int out_size, void* d_ws, size_t ws_size,
                              hipStream_t stream)
{
    const float* xg = (const float*)d_in[0];  // [B,I,K]
    const float* wg = (const float*)d_in[1];  // [N,I,D,K]
    if (n_in >= 2 && in_sizes[0] == NN * II * DD * KK) {
        const float* t = xg; xg = wg; wg = t;
    }
    float* outp = (float*)d_out;

    const size_t perB  = (size_t)NN * II * DD * 2;       // 368,640 B bf16 u per b
    const size_t p0B   = (size_t)BN * 160 * 4;           // 163,840
    const size_t p12B  = (size_t)BN * NCH * 160 * 4;     // 1,474,560 each
    size_t extra = p0B + 2 * p12B;
    size_t avail = (ws_size > extra) ? ws_size - extra : 0;
    int C = 256;
    if (avail < (size_t)256 * perB) {
        C = (int)(avail / perB);
        C &= ~15;
        if (C < 16) C = 16;
    }
    ushort_t* uws = (ushort_t*)d_ws;
    float* part0 = (float*)((char*)d_ws + (size_t)C * perB);
    float* part1 = part0 + (size_t)BN * 160;
    float* part2 = part1 + (size_t)BN * NCH * 160;

    for (int b0 = 0; b0 < BN; b0 += C) {
        int c = (BN - b0 < C) ? (BN - b0) : C;
        int c2 = c / 2;
        caps_uhat_s0<<<NN * c2, 256, 0, stream>>>(xg, wg, uws, part0, b0, c2);
        caps_sweep  <<<c * NCH, 256, 0, stream>>>(uws, part0, nullptr, part1, b0);
        caps_sweep  <<<c * NCH, 256, 0, stream>>>(uws, part0, part1,  part2, b0);
        caps_out    <<<c,       192, 0, stream>>>(part2, outp, b0);
    }
}

// Round 5
// 156.748 us; speedup vs baseline: 1.7966x; 1.3432x over previous
//
#include <hip/hip_runtime.h>
#include <stdint.h>

// CapsuleLayer dynamic routing, MI355X. fp32 in/out.
// B=256, N=10, I=1152, D=16, K(Din)=8, ROUTINGS=3.
// R5: K1 one-i-per-thread (MLP fix for the VGPR=32 serialization of R4);
// sweep0 partials via shfl+LDS per i-tile (part0[b][18][160]).
// Sweeps: 384-i chunks, register-lean (o from LDS, u re-unpacked) for occupancy.

#define BN 256
#define NN 10
#define II 1152
#define DD 16
#define KK 8
#define NT 18          // K1 i-tiles of 64
#define NCH 3          // sweep chunks
#define CHI 384        // i per sweep chunk (6 steps of 64)

typedef unsigned short ushort_t;
typedef unsigned int uint_t;

__device__ __forceinline__ float bflo(uint_t u) {
    union { uint_t i; float f; } v; v.i = u << 16; return v.f;
}
__device__ __forceinline__ float bfhi(uint_t u) {
    union { uint_t i; float f; } v; v.i = u & 0xffff0000u; return v.f;
}
__device__ __forceinline__ uint_t f2bf(float f) {  // RTNE bf16
    union { float f; uint_t i; } v; v.f = f;
    uint_t x = v.i;
    return (x + 0x7fffu + ((x >> 16) & 1u)) >> 16;
}

// ---------------- K1 + sweep0 partials --------------------------------------
// block = (i-tile of 64, b-quad), i-tile-major. 256 thr = 4 waves.
// lane = il*4+dq: thread owns (i = it*64 + wv*16 + il, d-quad dq), 4 b's.
// W row read: thread takes W[n][i][dq*4..dq*4+3][*] = 128 contiguous B;
// wave covers 8 KB contiguous. Stores: wave writes 512 B contiguous per (b,n).
// part0[b][it][n*16+d] = 0.1 * sum_{i in tile} u  (fp32, pre-pack values).
__global__ __launch_bounds__(256) void caps_uhat_s0(const float* __restrict__ xg,
                                                    const float* __restrict__ wg,
                                                    ushort_t* __restrict__ u,
                                                    float* __restrict__ part0,
                                                    int b0, int c4)
{
    __shared__ float red[16][NN][16];   // [wv*4+dq][n][bb*4+dj], 10 KB
    const int tid = threadIdx.x;
    const int lane = tid & 63, wv = tid >> 6;
    const int dq = lane & 3, il = lane >> 2;
    const int it = blockIdx.x / c4;
    const int bl = (blockIdx.x % c4) * 4;      // chunk-local b base (4 b's)
    const int i = it * 64 + wv * 16 + il;

    float xv[4][8];
#pragma unroll
    for (int bb = 0; bb < 4; ++bb) {
        const float4* xp = (const float4*)(xg + ((size_t)(b0 + bl + bb) * II + i) * KK);
        float4 x0 = xp[0], x1 = xp[1];
        xv[bb][0] = x0.x; xv[bb][1] = x0.y; xv[bb][2] = x0.z; xv[bb][3] = x0.w;
        xv[bb][4] = x1.x; xv[bb][5] = x1.y; xv[bb][6] = x1.z; xv[bb][7] = x1.w;
    }

    for (int n = 0; n < NN; ++n) {
        const float4* wp = (const float4*)(wg + (size_t)(n * II + i) * (DD * KK)) + dq * 8;
        float4 w[8];
#pragma unroll
        for (int j = 0; j < 8; ++j) w[j] = wp[j];

        float s[4][4];   // [bb][dj]
#pragma unroll
        for (int dj = 0; dj < 4; ++dj) {
            float4 wa = w[2 * dj], wb = w[2 * dj + 1];
#pragma unroll
            for (int bb = 0; bb < 4; ++bb) {
                s[bb][dj] = wa.x * xv[bb][0] + wa.y * xv[bb][1]
                          + wa.z * xv[bb][2] + wa.w * xv[bb][3]
                          + wb.x * xv[bb][4] + wb.y * xv[bb][5]
                          + wb.z * xv[bb][6] + wb.w * xv[bb][7];
            }
        }
        // store u (bf16): wave-contiguous 512 B per (b,n)
#pragma unroll
        for (int bb = 0; bb < 4; ++bb) {
            uint2 q;
            q.x = f2bf(s[bb][0]) | (f2bf(s[bb][1]) << 16);
            q.y = f2bf(s[bb][2]) | (f2bf(s[bb][3]) << 16);
            *(uint2*)(u + (((size_t)(bl + bb) * NN + n) * II + i) * DD + dq * 4) = q;
        }
        // reduce over the 16 il lanes (masks 4,8,16,32)
#pragma unroll
        for (int m = 4; m <= 32; m <<= 1)
#pragma unroll
            for (int bb = 0; bb < 4; ++bb)
#pragma unroll
                for (int dj = 0; dj < 4; ++dj)
                    s[bb][dj] += __shfl_xor(s[bb][dj], m, 64);
        if (il == 0) {
#pragma unroll
            for (int bb = 0; bb < 4; ++bb)
#pragma unroll
                for (int dj = 0; dj < 4; ++dj)
                    red[wv * 4 + dq][n][bb * 4 + dj] = s[bb][dj];
        }
    }
    __syncthreads();
#pragma unroll
    for (int idx = tid; idx < 640; idx += 256) {
        int bb = idx / 160, r = idx - bb * 160;
        int n = r >> 4, d = r & 15, q2 = d >> 2, dj = d & 3;
        float v = red[0 + q2][n][bb * 4 + dj] + red[4 + q2][n][bb * 4 + dj]
                + red[8 + q2][n][bb * 4 + dj] + red[12 + q2][n][bb * 4 + dj];
        part0[((size_t)(b0 + bl + bb) * NT + it) * 160 + r] = 0.1f * v;
    }
}

// ---- block reduction of sp[NN][4] over 64 groups -> 160 floats -------------
__device__ __forceinline__ void block_reduce_part(float sp[NN][4], int tid,
                                                  float* red,
                                                  float* __restrict__ partp)
{
#pragma unroll
    for (int m = 4; m <= 32; m <<= 1)
#pragma unroll
        for (int n = 0; n < NN; ++n)
#pragma unroll
            for (int j = 0; j < 4; ++j)
                sp[n][j] += __shfl_xor(sp[n][j], m, 64);

    const int lane = tid & 63, wv = tid >> 6, ld = tid & 3;
    if (lane < 4) {
#pragma unroll
        for (int n = 0; n < NN; ++n)
#pragma unroll
            for (int j = 0; j < 4; ++j)
                red[(wv * NN + n) * 16 + ld * 4 + j] = sp[n][j];
    }
    __syncthreads();
    if (tid < 160) {
        int n = tid >> 4, dd = tid & 15;
        float v = 0.f;
#pragma unroll
        for (int w = 0; w < 4; ++w) v += red[(w * NN + n) * 16 + dd];
        partp[tid] = v;
    }
}

// ---------------- sweep r=1,2 ----------------------------------------------
// o = squash(sum_{18} part0[b]);  if p1: o += squash(sum_{3} p1[b]).
// c = softmax_n(<o,u>), partial s = sum c*u over this 384-i chunk.
__global__ __launch_bounds__(256) void caps_sweep(const ushort_t* __restrict__ u,
                                                  const float* __restrict__ p0,
                                                  const float* __restrict__ p1,
                                                  float* __restrict__ pout, int b0)
{
    __shared__ float red[4 * 160];
    __shared__ float o_s[160];
    const int tid = threadIdx.x, g = tid >> 2, ld = tid & 3;
    const int cb = blockIdx.x / NCH, ch = blockIdx.x % NCH;
    const int b = b0 + cb;
    const ushort_t* ub = u + (size_t)cb * (NN * II * DD);

    if (tid < 160) {
        float v = 0.f;
#pragma unroll
        for (int t = 0; t < NT; ++t)
            v += p0[((size_t)b * NT + t) * 160 + tid];
        float sq = v * v;
#pragma unroll
        for (int m = 1; m <= 8; m <<= 1) sq += __shfl_xor(sq, m, 64);
        float o = v * (sqrtf(sq) / (1.0f + sq));
        if (p1) {
            float v1 = 0.f;
#pragma unroll
            for (int c2 = 0; c2 < NCH; ++c2)
                v1 += p1[((size_t)b * NCH + c2) * 160 + tid];
            float sq1 = v1 * v1;
#pragma unroll
            for (int m = 1; m <= 8; m <<= 1) sq1 += __shfl_xor(sq1, m, 64);
            o += v1 * (sqrtf(sq1) / (1.0f + sq1));
        }
        o_s[tid] = o;
    }
    __syncthreads();

    float sp[NN][4];
#pragma unroll
    for (int n = 0; n < NN; ++n)
#pragma unroll
        for (int j = 0; j < 4; ++j) sp[n][j] = 0.f;

    for (int step = 0; step < CHI / 64; ++step) {
        int i = ch * CHI + step * 64 + g;
        uint2 r[NN];
#pragma unroll
        for (int n = 0; n < NN; ++n)
            r[n] = *(const uint2*)(ub + ((size_t)(n * II + i)) * DD + ld * 4);

        float p[NN];
#pragma unroll
        for (int n = 0; n < NN; ++n) {
            float4 o4 = *(const float4*)&o_s[(n << 4) + (ld << 2)];  // broadcast
            p[n] = bflo(r[n].x) * o4.x + bfhi(r[n].x) * o4.y
                 + bflo(r[n].y) * o4.z + bfhi(r[n].y) * o4.w;
        }
        float a[NN];
#pragma unroll
        for (int n = 0; n < NN; ++n) {
            float t2 = p[n] + __shfl_xor(p[n], 1, 64);
            a[n] = t2 + __shfl_xor(t2, 2, 64);
        }
        float m = a[0];
#pragma unroll
        for (int n = 1; n < NN; ++n) m = fmaxf(m, a[n]);
        float c[NN], ssum = 0.f;
#pragma unroll
        for (int n = 0; n < NN; ++n) { c[n] = __expf(a[n] - m); ssum += c[n]; }
        float inv = 1.0f / ssum;
#pragma unroll
        for (int n = 0; n < NN; ++n) {
            float w = c[n] * inv;
            sp[n][0] += w * bflo(r[n].x); sp[n][1] += w * bfhi(r[n].x);
            sp[n][2] += w * bflo(r[n].y); sp[n][3] += w * bfhi(r[n].y);
        }
    }
    block_reduce_part(sp, tid, red, pout + ((size_t)b * NCH + ch) * 160);
}

// ---------------- output: squash(sum_ch part2) ------------------------------
__global__ __launch_bounds__(192) void caps_out(const float* __restrict__ p2,
                                                float* __restrict__ out, int b0)
{
    const int b = b0 + blockIdx.x;
    const int t = threadIdx.x;
    if (t < 160) {
        float v = 0.f;
#pragma unroll
        for (int ch = 0; ch < NCH; ++ch)
            v += p2[((size_t)b * NCH + ch) * 160 + t];
        float sq = v * v;
#pragma unroll
        for (int m = 1; m <= 8; m <<= 1) sq += __shfl_xor(sq, m, 64);
        out[(size_t)b * 160 + t] = v * (sqrtf(sq) / (1.0f + sq));
    }
}

extern "C" void kernel_launch(void* const* d_in, const int* in_sizes, int n_in,
                              void* d_out, int out_size, void* d_ws, size_t ws_size,
                              hipStream_t stream)
{
    const float* xg = (const float*)d_in[0];  // [B,I,K]
    const float* wg = (const float*)d_in[1];  // [N,I,D,K]
    if (n_in >= 2 && in_sizes[0] == NN * II * DD * KK) {
        const float* t = xg; xg = wg; wg = t;
    }
    float* outp = (float*)d_out;

    const size_t perB  = (size_t)NN * II * DD * 2;       // 368,640 B bf16 u per b
    const size_t p0B   = (size_t)BN * NT * 160 * 4;      // 2,949,120
    const size_t p12B  = (size_t)BN * NCH * 160 * 4;     // 491,520 each
    size_t extra = p0B + 2 * p12B;
    size_t avail = (ws_size > extra) ? ws_size - extra : 0;
    int C = 256;
    if (avail < (size_t)256 * perB) {
        C = (int)(avail / perB);
        C &= ~15;
        if (C < 16) C = 16;
    }
    ushort_t* uws = (ushort_t*)d_ws;
    float* part0 = (float*)((char*)d_ws + (size_t)C * perB);
    float* part1 = part0 + (size_t)BN * NT * 160;
    float* part2 = part1 + (size_t)BN * NCH * 160;

    for (int b0 = 0; b0 < BN; b0 += C) {
        int c = (BN - b0 < C) ? (BN - b0) : C;
        int c4 = c / 4;
        caps_uhat_s0<<<NT * c4, 256, 0, stream>>>(xg, wg, uws, part0, b0, c4);
        caps_sweep  <<<c * NCH, 256, 0, stream>>>(uws, part0, nullptr, part1, b0);
        caps_sweep  <<<c * NCH, 256, 0, stream>>>(uws, part0, part1,  part2, b0);
        caps_out    <<<c,       192, 0, stream>>>(part2, outp, b0);
    }
}